// Round 4
// baseline (2170.876 us; speedup 1.0000x reference)
//
#include <hip/hip_runtime.h>
#include <hip/hip_bf16.h>

#define N_NODES 200000
#define N_EDGES 4000000
#define R_REL   4
#define D_DIM   64
#define G_GRAPHS 64
#define C_CLS   10
#define NR      (N_NODES * R_REL)      // 800000
#define SCAN_CHUNK 2048
#define NB      ((NR + SCAN_CHUNK - 1) / SCAN_CHUNK)   // 391
#define LBN     64                      // nodes per layer block
#define POOL_BLOCKS 256

__device__ __forceinline__ unsigned short to_bf16(float x) {
    __hip_bfloat16 b = __float2bfloat16(x);
    return *(unsigned short*)&b;
}

// ---------------- preprocessing: CSR build over (tgt*R + etype) ----------------

__global__ void k_count(const int* __restrict__ tgt, const int* __restrict__ et,
                        int* __restrict__ cnt) {
    int e = blockIdx.x * blockDim.x + threadIdx.x;
    if (e < N_EDGES) atomicAdd(&cnt[tgt[e] * R_REL + et[e]], 1);
}

__global__ void k_scan1(const int* __restrict__ cnt, int* __restrict__ off,
                        int* __restrict__ bsum) {
    __shared__ int lds[256];
    int tid = threadIdx.x;
    int base = blockIdx.x * SCAN_CHUNK + tid * 8;
    int v[8];
    int s = 0;
#pragma unroll
    for (int i = 0; i < 8; ++i) {
        int idx = base + i;
        v[i] = (idx < NR) ? cnt[idx] : 0;
        s += v[i];
    }
    lds[tid] = s;
    __syncthreads();
    for (int d = 1; d < 256; d <<= 1) {
        int t = (tid >= d) ? lds[tid - d] : 0;
        __syncthreads();
        lds[tid] += t;
        __syncthreads();
    }
    int excl = lds[tid] - s;
    if (tid == 255) bsum[blockIdx.x] = lds[255];
    int run = excl;
#pragma unroll
    for (int i = 0; i < 8; ++i) {
        int idx = base + i;
        if (idx < NR) off[idx] = run;
        run += v[i];
    }
}

__global__ void k_scan2(int* __restrict__ bsum) {
    __shared__ int lds[NB];
    for (int i = threadIdx.x; i < NB; i += blockDim.x) lds[i] = bsum[i];
    __syncthreads();
    if (threadIdx.x == 0) {
        int acc = 0;
        for (int i = 0; i < NB; ++i) { int t = lds[i]; lds[i] = acc; acc += t; }
    }
    __syncthreads();
    for (int i = threadIdx.x; i < NB; i += blockDim.x) bsum[i] = lds[i];
}

__global__ void k_scan3(const int* __restrict__ cnt, int* __restrict__ off,
                        const int* __restrict__ bsum, int* __restrict__ cursor,
                        float* __restrict__ invc, int* __restrict__ edgePacked) {
    int idx = blockIdx.x * blockDim.x + threadIdx.x;
    if (idx < NR) {
        int o = off[idx] + bsum[idx / SCAN_CHUNK];
        off[idx] = o;
        cursor[idx] = o;
        int c = cnt[idx];
        invc[idx] = 1.0f / (float)(c > 0 ? c : 1);
    }
    if (idx == 0) off[NR] = N_EDGES;
    if (idx < 64) edgePacked[N_EDGES + idx] = 0;   // pad: src 0, row 0
}

// pack per-edge: (src << 8) | (key & 255)  — local m-row within the owning block
__global__ void k_scatter(const int* __restrict__ src, const int* __restrict__ tgt,
                          const int* __restrict__ et, int* __restrict__ cursor,
                          int* __restrict__ edgePacked) {
    int e = blockIdx.x * blockDim.x + threadIdx.x;
    if (e < N_EDGES) {
        int key = tgt[e] * R_REL + et[e];
        int pos = atomicAdd(&cursor[key], 1);
        edgePacked[pos] = (src[e] << 8) | (key & 255);
    }
}

// ---------------- embedding: fp32 h + bf16 shadow copy ----------------

__global__ void k_embed(const int* __restrict__ xop, const int* __restrict__ xcat,
                        const float4* __restrict__ opemb, const float4* __restrict__ catemb,
                        float4* __restrict__ h, ushort4* __restrict__ hb) {
    int i = blockIdx.x * blockDim.x + threadIdx.x;   // over N*16 float4s
    if (i < N_NODES * 16) {
        int n = i >> 4, q = i & 15;
        float4 a = opemb[xop[n] * 16 + q];
        float4 b = catemb[xcat[n] * 16 + q];
        float4 r = make_float4(a.x + b.x, a.y + b.y, a.z + b.z, a.w + b.w);
        h[i] = r;
        ushort4 ub;
        ub.x = to_bf16(r.x); ub.y = to_bf16(r.y);
        ub.z = to_bf16(r.z); ub.w = to_bf16(r.w);
        hb[i] = ub;
    }
}

// graph boundaries from sorted batch (no atomics)
__global__ void k_bounds(const int* __restrict__ batch, int* __restrict__ start) {
    int i = blockIdx.x * blockDim.x + threadIdx.x;
    if (i >= N_NODES) return;
    int b = batch[i];
    if (i == 0) {
        for (int g = 0; g <= b; ++g) start[g] = 0;
    } else {
        int p = batch[i - 1];
        for (int g = p + 1; g <= b; ++g) start[g] = i;
    }
    if (i == N_NODES - 1) {
        for (int g = b + 1; g <= G_GRAPHS; ++g) start[g] = N_NODES;
    }
}

// ---------------- fused RGCN layer ----------------
// Phase A: per-wave contiguous edge chunk, 16-deep unrolled bf16 row gathers,
// register run-accumulation (edges sorted by key), ds_add only on row change.
// Phase B: 5 GEMM passes (4 relations + root, all fp32) with weights in LDS.

template <int RELU>  // RELU also gates the bf16 shadow write (last layer skips it)
__global__ __launch_bounds__(1024, 8) void k_layer(
    const float* __restrict__ h_in,            // fp32 (root pass)
    const unsigned short* __restrict__ hb_in,  // bf16 (gathers)
    float* __restrict__ h_out,
    unsigned short* __restrict__ hb_out,
    const int* __restrict__ off, const int* __restrict__ edgePacked,
    const float* __restrict__ invc,
    const float* __restrict__ w,     // [4][64][64]
    const float* __restrict__ root,  // [64][64]
    const float* __restrict__ bias)  // [64]
{
    __shared__ float m_lds[LBN * R_REL * D_DIM];   // 65536 B
    __shared__ float w_lds[D_DIM * D_DIM];         // 16384 B

    const int tid   = threadIdx.x;
    const int lane  = tid & 63;
    const int wid   = tid >> 6;            // 0..15
    const int nbase = blockIdx.x * LBN;
    const int rbase = nbase * R_REL;       // first global key of this block

    // zero the aggregation table
#pragma unroll
    for (int i = 0; i < 16; ++i) m_lds[tid + i * 1024] = 0.f;
    __syncthreads();

    // ---- edge aggregation: per-wave contiguous chunk, run-accumulate ----
    const int eBase = off[rbase];
    const int eEnd  = off[rbase + LBN * R_REL];
    const int ecnt  = eEnd - eBase;
    const int chunk = (ecnt + 15) >> 4;
    const int c0    = eBase + wid * chunk;
    int c1 = c0 + chunk; if (c1 > eEnd) c1 = eEnd;

    float acc = 0.f;
    int curRow = -1;
    for (int base = c0; base < c1; base += 16) {
        int p[16];
#pragma unroll
        for (int k = 0; k < 16; ++k) p[k] = edgePacked[base + k];  // uniform-addr loads (pad-safe)
        int s[16];
#pragma unroll
        for (int k = 0; k < 16; ++k) s[k] = __builtin_amdgcn_readfirstlane(p[k]);
        float v[16];
#pragma unroll
        for (int k = 0; k < 16; ++k) {
            unsigned int u = hb_in[(s[k] >> 8) * D_DIM + lane];
            v[k] = __uint_as_float(u << 16);
        }
        const int rem = c1 - base;
#pragma unroll
        for (int k = 0; k < 16; ++k) {
            float vv = (k < rem) ? v[k] : 0.f;
            int rk = s[k] & 255;
            if (rk != curRow) {
                if (curRow >= 0) atomicAdd(&m_lds[curRow * D_DIM + lane], acc);
                curRow = rk;
                acc = vv;
            } else {
                acc += vv;
            }
        }
    }
    if (curRow >= 0) atomicAdd(&m_lds[curRow * D_DIM + lane], acc);
    __syncthreads();

    // ---- scale sums -> means ----
#pragma unroll
    for (int i = 0; i < 16; ++i) {
        int idx = tid + i * 1024;
        m_lds[idx] *= invc[rbase + (idx >> 6)];
    }
    __syncthreads();

    // ---- 5 GEMM passes (4 relations + root), fp32 ----
    float acc0 = 0.f, acc1 = 0.f, acc2 = 0.f, acc3 = 0.f;
    for (int r = 0; r < 5; ++r) {
        const float4* wsrc = (const float4*)((r < 4) ? (w + r * 4096) : root);
        ((float4*)w_lds)[tid] = wsrc[tid];
        if (r == 4) {
            // stage this block's own fp32 h rows into the (now consumed) front of m_lds
#pragma unroll
            for (int i = 0; i < 4; ++i) {
                int idx = tid + i * 1024;            // n*64 + d
                m_lds[idx] = h_in[nbase * D_DIM + idx];
            }
        }
        __syncthreads();

#pragma unroll
        for (int d4 = 0; d4 < D_DIM; d4 += 4) {
            float w0 = w_lds[(d4 + 0) * D_DIM + lane];
            float w1 = w_lds[(d4 + 1) * D_DIM + lane];
            float w2 = w_lds[(d4 + 2) * D_DIM + lane];
            float w3 = w_lds[(d4 + 3) * D_DIM + lane];
#pragma unroll
            for (int j = 0; j < 4; ++j) {
                int n = wid + 16 * j;
                int rowbase = (r < 4) ? ((n * R_REL + r) * D_DIM) : (n * D_DIM);
                const float4 m = *(const float4*)&m_lds[rowbase + d4];
                float a = (j == 0) ? acc0 : (j == 1) ? acc1 : (j == 2) ? acc2 : acc3;
                a = fmaf(m.x, w0, a);
                a = fmaf(m.y, w1, a);
                a = fmaf(m.z, w2, a);
                a = fmaf(m.w, w3, a);
                if (j == 0) acc0 = a; else if (j == 1) acc1 = a;
                else if (j == 2) acc2 = a; else acc3 = a;
            }
        }
        __syncthreads();
    }

    // ---- epilogue: fp32 out + bf16 shadow ----
    float b = bias[lane];
#pragma unroll
    for (int j = 0; j < 4; ++j) {
        float a = (j == 0) ? acc0 : (j == 1) ? acc1 : (j == 2) ? acc2 : acc3;
        float v = a + b;
        if (RELU) v = fmaxf(v, 0.f);
        int n = nbase + wid + 16 * j;
        h_out[n * D_DIM + lane] = v;
        if (RELU) hb_out[n * D_DIM + lane] = to_bf16(v);
    }
}

// ---------------- pooling: run-accumulated (batch is sorted) ----------------

__global__ __launch_bounds__(1024) void k_pool(const float* __restrict__ h,
                                               const int* __restrict__ batch,
                                               float* __restrict__ partial) {
    __shared__ float bin[G_GRAPHS * D_DIM];   // 16 KB
    int tid = threadIdx.x, lane = tid & 63, wid = tid >> 6;
    for (int i = tid; i < G_GRAPHS * D_DIM; i += 1024) bin[i] = 0.f;
    __syncthreads();
    const int per = (N_NODES + POOL_BLOCKS - 1) / POOL_BLOCKS;
    int n0 = blockIdx.x * per;
    int n1 = n0 + per; if (n1 > N_NODES) n1 = N_NODES;
    int cntw = n1 - n0;
    int sub = (cntw + 15) >> 4;
    int w0 = n0 + wid * sub;
    int w1 = w0 + sub; if (w1 > n1) w1 = n1;

    float acc = 0.f;
    int cur = -1;
    for (int n = w0; n < w1; ++n) {
        int b = __builtin_amdgcn_readfirstlane(batch[n]);
        float v = h[n * D_DIM + lane];
        if (b != cur) {
            if (cur >= 0) atomicAdd(&bin[cur * D_DIM + lane], acc);
            cur = b;
            acc = v;
        } else {
            acc += v;
        }
    }
    if (cur >= 0) atomicAdd(&bin[cur * D_DIM + lane], acc);
    __syncthreads();
    for (int i = tid; i < G_GRAPHS * D_DIM; i += 1024)
        partial[blockIdx.x * (G_GRAPHS * D_DIM) + i] = bin[i];
}

__global__ void k_pool_reduce(const float* __restrict__ partial,
                              float* __restrict__ pooled) {
    int i = blockIdx.x * blockDim.x + threadIdx.x;   // 4096
    if (i < G_GRAPHS * D_DIM) {
        float s = 0.f;
        for (int b = 0; b < POOL_BLOCKS; ++b) s += partial[b * (G_GRAPHS * D_DIM) + i];
        pooled[i] = s;
    }
}

// ---------------- head ----------------

__global__ void k_head(const float* __restrict__ pooled, const int* __restrict__ start,
                       const float* __restrict__ fc1w, const float* __restrict__ fc1b,
                       const float* __restrict__ fc2w, const float* __restrict__ fc2b,
                       float* __restrict__ out) {
    __shared__ float p[G_GRAPHS][D_DIM];
    __shared__ float hf[G_GRAPHS][D_DIM];
    __shared__ float sc[G_GRAPHS][C_CLS];
    int t = threadIdx.x;

    for (int i = t; i < G_GRAPHS * D_DIM; i += 1024) {
        int g = i >> 6;
        int c = start[g + 1] - start[g];
        p[g][i & 63] = pooled[i] / (float)(c > 0 ? c : 1);
    }
    __syncthreads();

    for (int i = t; i < G_GRAPHS * D_DIM; i += 1024) {
        int g = i >> 6, o = i & 63;
        float a = fc1b[o];
#pragma unroll
        for (int d = 0; d < D_DIM; ++d) a = fmaf(p[g][d], fc1w[d * D_DIM + o], a);
        hf[g][o] = fmaxf(a, 0.f);
    }
    __syncthreads();

    if (t < G_GRAPHS * C_CLS) {
        int g = t / C_CLS, c = t % C_CLS;
        float a = fc2b[c];
#pragma unroll
        for (int d = 0; d < D_DIM; ++d) a = fmaf(hf[g][d], fc2w[d * C_CLS + c], a);
        sc[g][c] = a;
    }
    __syncthreads();

    if (t < G_GRAPHS) {
        float m = -1e30f;
#pragma unroll
        for (int c = 0; c < C_CLS; ++c) m = fmaxf(m, sc[t][c]);
        float s = 0.f;
#pragma unroll
        for (int c = 0; c < C_CLS; ++c) s += expf(sc[t][c] - m);
        float lse = m + logf(s);
#pragma unroll
        for (int c = 0; c < C_CLS; ++c) out[t * C_CLS + c] = sc[t][c] - lse;
    }
}

// ---------------- launch ----------------

extern "C" void kernel_launch(void* const* d_in, const int* in_sizes, int n_in,
                              void* d_out, int out_size, void* d_ws, size_t ws_size,
                              hipStream_t stream) {
    const int*   x_op    = (const int*)d_in[0];
    const int*   x_cat   = (const int*)d_in[1];
    const int*   eidx    = (const int*)d_in[2];
    const int*   src     = eidx;
    const int*   tgt     = eidx + N_EDGES;
    const int*   etype   = (const int*)d_in[3];
    const int*   batch   = (const int*)d_in[4];
    const float* op_emb  = (const float*)d_in[5];
    const float* cat_emb = (const float*)d_in[6];
    const float* w1 = (const float*)d_in[7];
    const float* r1 = (const float*)d_in[8];
    const float* b1 = (const float*)d_in[9];
    const float* w2 = (const float*)d_in[10];
    const float* r2 = (const float*)d_in[11];
    const float* b2 = (const float*)d_in[12];
    const float* w3 = (const float*)d_in[13];
    const float* r3 = (const float*)d_in[14];
    const float* b3 = (const float*)d_in[15];
    const float* fc1w = (const float*)d_in[16];
    const float* fc1b = (const float*)d_in[17];
    const float* fc2w = (const float*)d_in[18];
    const float* fc2b = (const float*)d_in[19];
    float* out = (float*)d_out;

    char* ws = (char*)d_ws;
    size_t o = 0;
    auto alloc = [&](size_t bytes) -> void* {
        o = (o + 255) & ~(size_t)255;
        void* p = ws + o;
        o += bytes;
        return p;
    };

    int*   cnt        = (int*)alloc((size_t)NR * 4);
    int*   off        = (int*)alloc((size_t)(NR + 1) * 4);
    int*   cursor     = (int*)alloc((size_t)NR * 4);
    float* invc       = (float*)alloc((size_t)NR * 4);
    int*   bsum       = (int*)alloc((size_t)NB * 4 + 256);
    int*   edgePacked = (int*)alloc((size_t)(N_EDGES + 64) * 4);
    float* h0         = (float*)alloc((size_t)N_NODES * D_DIM * 4);
    float* h1         = (float*)alloc((size_t)N_NODES * D_DIM * 4);
    unsigned short* hb0 = (unsigned short*)alloc((size_t)N_NODES * D_DIM * 2);
    unsigned short* hb1 = (unsigned short*)alloc((size_t)N_NODES * D_DIM * 2);
    float* partial    = (float*)alloc((size_t)POOL_BLOCKS * G_GRAPHS * D_DIM * 4);
    float* pooled     = (float*)alloc((size_t)G_GRAPHS * D_DIM * 4);
    int*   startg     = (int*)alloc((size_t)(G_GRAPHS + 1) * 4);

    hipMemsetAsync(cnt, 0, (size_t)NR * 4, stream);

    k_count<<<(N_EDGES + 255) / 256, 256, 0, stream>>>(tgt, etype, cnt);
    k_scan1<<<NB, 256, 0, stream>>>(cnt, off, bsum);
    k_scan2<<<1, 256, 0, stream>>>(bsum);
    k_scan3<<<(NR + 255) / 256, 256, 0, stream>>>(cnt, off, bsum, cursor, invc, edgePacked);
    k_scatter<<<(N_EDGES + 255) / 256, 256, 0, stream>>>(src, tgt, etype, cursor, edgePacked);

    k_embed<<<(N_NODES * 16 + 255) / 256, 256, 0, stream>>>(
        x_op, x_cat, (const float4*)op_emb, (const float4*)cat_emb,
        (float4*)h0, (ushort4*)hb0);
    k_bounds<<<(N_NODES + 255) / 256, 256, 0, stream>>>(batch, startg);

    k_layer<1><<<N_NODES / LBN, 1024, 0, stream>>>(
        h0, hb0, h1, hb1, off, edgePacked, invc, w1, r1, b1);
    k_layer<1><<<N_NODES / LBN, 1024, 0, stream>>>(
        h1, hb1, h0, hb0, off, edgePacked, invc, w2, r2, b2);
    k_layer<0><<<N_NODES / LBN, 1024, 0, stream>>>(
        h0, hb0, h1, hb1, off, edgePacked, invc, w3, r3, b3);

    k_pool<<<POOL_BLOCKS, 1024, 0, stream>>>(h1, batch, partial);
    k_pool_reduce<<<(G_GRAPHS * D_DIM + 255) / 256, 256, 0, stream>>>(partial, pooled);
    k_head<<<1, 1024, 0, stream>>>(pooled, startg, fc1w, fc1b, fc2w, fc2b, out);
}

// Round 6
// 1572.499 us; speedup vs baseline: 1.3805x; 1.3805x over previous
//
#include <hip/hip_runtime.h>
#include <hip/hip_bf16.h>

#define N_NODES 200000
#define N_EDGES 4000000
#define R_REL   4
#define D_DIM   64
#define G_GRAPHS 64
#define C_CLS   10
#define NR      (N_NODES * R_REL)      // 800000
#define SCAN_CHUNK 2048
#define NB      ((NR + SCAN_CHUNK - 1) / SCAN_CHUNK)   // 391
#define LBN     64                      // nodes per GEMM tile
#define POOL_BLOCKS 128

__device__ __forceinline__ unsigned short to_bf16(float x) {
    __hip_bfloat16 b = __float2bfloat16(x);
    return *(unsigned short*)&b;
}

// ---------------- preprocessing: CSR build over (tgt*R + etype) ----------------

__global__ void k_count(const int* __restrict__ tgt, const int* __restrict__ et,
                        int* __restrict__ cnt) {
    int e = blockIdx.x * blockDim.x + threadIdx.x;
    if (e < N_EDGES) atomicAdd(&cnt[tgt[e] * R_REL + et[e]], 1);
}

__global__ void k_scan1(const int* __restrict__ cnt, int* __restrict__ off,
                        int* __restrict__ bsum) {
    __shared__ int lds[256];
    int tid = threadIdx.x;
    int base = blockIdx.x * SCAN_CHUNK + tid * 8;
    int v[8];
    int s = 0;
#pragma unroll
    for (int i = 0; i < 8; ++i) {
        int idx = base + i;
        v[i] = (idx < NR) ? cnt[idx] : 0;
        s += v[i];
    }
    lds[tid] = s;
    __syncthreads();
    for (int d = 1; d < 256; d <<= 1) {
        int t = (tid >= d) ? lds[tid - d] : 0;
        __syncthreads();
        lds[tid] += t;
        __syncthreads();
    }
    int excl = lds[tid] - s;
    if (tid == 255) bsum[blockIdx.x] = lds[255];
    int run = excl;
#pragma unroll
    for (int i = 0; i < 8; ++i) {
        int idx = base + i;
        if (idx < NR) off[idx] = run;
        run += v[i];
    }
}

__global__ void k_scan2(int* __restrict__ bsum) {
    __shared__ int lds[NB];
    for (int i = threadIdx.x; i < NB; i += blockDim.x) lds[i] = bsum[i];
    __syncthreads();
    if (threadIdx.x == 0) {
        int acc = 0;
        for (int i = 0; i < NB; ++i) { int t = lds[i]; lds[i] = acc; acc += t; }
    }
    __syncthreads();
    for (int i = threadIdx.x; i < NB; i += blockDim.x) bsum[i] = lds[i];
}

__global__ void k_scan3(const int* __restrict__ cnt, int* __restrict__ off,
                        const int* __restrict__ bsum, int* __restrict__ cursor,
                        float* __restrict__ invc) {
    int idx = blockIdx.x * blockDim.x + threadIdx.x;
    if (idx < NR) {
        int o = off[idx] + bsum[idx / SCAN_CHUNK];
        off[idx] = o;
        cursor[idx] = o;
        int c = cnt[idx];
        invc[idx] = 1.0f / (float)(c > 0 ? c : 1);
    }
    if (idx == 0) off[NR] = N_EDGES;
}

__global__ void k_scatter(const int* __restrict__ src, const int* __restrict__ tgt,
                          const int* __restrict__ et, int* __restrict__ cursor,
                          int* __restrict__ srcSorted) {
    int e = blockIdx.x * blockDim.x + threadIdx.x;
    if (e < N_EDGES) {
        int key = tgt[e] * R_REL + et[e];
        int pos = atomicAdd(&cursor[key], 1);
        srcSorted[pos] = src[e];
    }
}

// ---------------- embedding -> bf16 h ----------------

__global__ void k_embed(const int* __restrict__ xop, const int* __restrict__ xcat,
                        const float4* __restrict__ opemb, const float4* __restrict__ catemb,
                        ushort4* __restrict__ hb) {
    int i = blockIdx.x * blockDim.x + threadIdx.x;   // over N*16 quads
    if (i < N_NODES * 16) {
        int n = i >> 4, q = i & 15;
        float4 a = opemb[xop[n] * 16 + q];
        float4 b = catemb[xcat[n] * 16 + q];
        ushort4 ub;
        ub.x = to_bf16(a.x + b.x); ub.y = to_bf16(a.y + b.y);
        ub.z = to_bf16(a.z + b.z); ub.w = to_bf16(a.w + b.w);
        hb[i] = ub;
    }
}

// graph boundaries from sorted batch (no atomics)
__global__ void k_bounds(const int* __restrict__ batch, int* __restrict__ start) {
    int i = blockIdx.x * blockDim.x + threadIdx.x;
    if (i >= N_NODES) return;
    int b = batch[i];
    if (i == 0) {
        for (int g = 0; g <= b; ++g) start[g] = 0;
    } else {
        int p = batch[i - 1];
        for (int g = p + 1; g <= b; ++g) start[g] = i;
    }
    if (i == N_NODES - 1) {
        for (int g = b + 1; g <= G_GRAPHS; ++g) start[g] = N_NODES;
    }
}

// ---------------- phase A: per-key mean aggregation ----------------
// One wave = 8 consecutive (node,rel) keys. lane = (g = lane>>3, q = lane&7):
// group g owns key wave*8+g, quad q owns channels [8q..8q+8). Per loop iter a
// lane issues one dwordx4 (16B of its group's edge row) -> the wave covers
// 8 edges' full 128B rows per instruction. Register-only accumulation.

__global__ __launch_bounds__(256) void k_agg(
    const unsigned short* __restrict__ hb_in,   // [N][64] bf16
    const int* __restrict__ off,
    const int* __restrict__ srcSorted,
    const float* __restrict__ invc,
    unsigned short* __restrict__ m_out)         // [NR][64] bf16 (means)
{
    const int wave = (blockIdx.x * 256 + threadIdx.x) >> 6;
    const int lane = threadIdx.x & 63;
    const int g = lane >> 3, q = lane & 7;
    const int key = wave * 8 + g;               // grid sized so key < NR

    const int e0 = off[key];
    const int e1 = off[key + 1];

    float acc[8];
#pragma unroll
    for (int i = 0; i < 8; ++i) acc[i] = 0.f;

    const unsigned short* base = hb_in + q * 8;

    int e = e0;
    for (; e + 2 <= e1; e += 2) {
        int s0 = srcSorted[e];
        int s1 = srcSorted[e + 1];
        uint4 u = *(const uint4*)(base + (size_t)s0 * D_DIM);
        uint4 v = *(const uint4*)(base + (size_t)s1 * D_DIM);
        acc[0] += __uint_as_float(u.x << 16);
        acc[1] += __uint_as_float(u.x & 0xFFFF0000u);
        acc[2] += __uint_as_float(u.y << 16);
        acc[3] += __uint_as_float(u.y & 0xFFFF0000u);
        acc[4] += __uint_as_float(u.z << 16);
        acc[5] += __uint_as_float(u.z & 0xFFFF0000u);
        acc[6] += __uint_as_float(u.w << 16);
        acc[7] += __uint_as_float(u.w & 0xFFFF0000u);
        acc[0] += __uint_as_float(v.x << 16);
        acc[1] += __uint_as_float(v.x & 0xFFFF0000u);
        acc[2] += __uint_as_float(v.y << 16);
        acc[3] += __uint_as_float(v.y & 0xFFFF0000u);
        acc[4] += __uint_as_float(v.z << 16);
        acc[5] += __uint_as_float(v.z & 0xFFFF0000u);
        acc[6] += __uint_as_float(v.w << 16);
        acc[7] += __uint_as_float(v.w & 0xFFFF0000u);
    }
    if (e < e1) {
        int s0 = srcSorted[e];
        uint4 u = *(const uint4*)(base + (size_t)s0 * D_DIM);
        acc[0] += __uint_as_float(u.x << 16);
        acc[1] += __uint_as_float(u.x & 0xFFFF0000u);
        acc[2] += __uint_as_float(u.y << 16);
        acc[3] += __uint_as_float(u.y & 0xFFFF0000u);
        acc[4] += __uint_as_float(u.z << 16);
        acc[5] += __uint_as_float(u.z & 0xFFFF0000u);
        acc[6] += __uint_as_float(u.w << 16);
        acc[7] += __uint_as_float(u.w & 0xFFFF0000u);
    }

    const float iv = invc[key];
    uint4 o;
    o.x = (unsigned int)to_bf16(acc[0] * iv) | ((unsigned int)to_bf16(acc[1] * iv) << 16);
    o.y = (unsigned int)to_bf16(acc[2] * iv) | ((unsigned int)to_bf16(acc[3] * iv) << 16);
    o.z = (unsigned int)to_bf16(acc[4] * iv) | ((unsigned int)to_bf16(acc[5] * iv) << 16);
    o.w = (unsigned int)to_bf16(acc[6] * iv) | ((unsigned int)to_bf16(acc[7] * iv) << 16);
    *(uint4*)(m_out + (size_t)key * D_DIM + q * 8) = o;
}

// ---------------- phase B: 5-pass tile GEMM (all-bf16 inputs, fp32 math) ----------------

template <int RELU>
__global__ __launch_bounds__(1024, 2) void k_trans(
    const unsigned short* __restrict__ hb_in,  // [N][64] bf16 (root pass)
    const unsigned short* __restrict__ m_in,   // [NR][64] bf16 means
    unsigned short* __restrict__ hb_out,       // [N][64] bf16
    const float* __restrict__ w,     // [4][64][64]
    const float* __restrict__ root,  // [64][64]
    const float* __restrict__ bias)  // [64]
{
    __shared__ float m_lds[LBN * R_REL * D_DIM];   // 65536 B
    __shared__ float w_lds[D_DIM * D_DIM];         // 16384 B

    const int tid   = threadIdx.x;
    const int lane  = tid & 63;
    const int wid   = tid >> 6;            // 0..15
    const int nbase = blockIdx.x * LBN;
    const int rbase = nbase * R_REL;       // first key of this tile

    // stage m tile (16384 bf16 -> fp32), coalesced
    const size_t mbase = (size_t)rbase * D_DIM;
#pragma unroll
    for (int i = 0; i < 16; ++i) {
        unsigned int u = m_in[mbase + tid + i * 1024];
        m_lds[tid + i * 1024] = __uint_as_float(u << 16);
    }
    // first pass's barrier below covers this staging

    // ---- 5 GEMM passes (4 relations + root), fp32 ----
    float acc0 = 0.f, acc1 = 0.f, acc2 = 0.f, acc3 = 0.f;
    for (int r = 0; r < 5; ++r) {
        const float4* wsrc = (const float4*)((r < 4) ? (w + r * 4096) : root);
        ((float4*)w_lds)[tid] = wsrc[tid];
        if (r == 4) {
            // stage this tile's own h rows (bf16) into the consumed front of m_lds
#pragma unroll
            for (int i = 0; i < 4; ++i) {
                int idx = tid + i * 1024;            // n*64 + d
                unsigned int u = hb_in[(size_t)nbase * D_DIM + idx];
                m_lds[idx] = __uint_as_float(u << 16);
            }
        }
        __syncthreads();

#pragma unroll
        for (int d4 = 0; d4 < D_DIM; d4 += 4) {
            float w0 = w_lds[(d4 + 0) * D_DIM + lane];
            float w1 = w_lds[(d4 + 1) * D_DIM + lane];
            float w2 = w_lds[(d4 + 2) * D_DIM + lane];
            float w3 = w_lds[(d4 + 3) * D_DIM + lane];
#pragma unroll
            for (int j = 0; j < 4; ++j) {
                int n = wid + 16 * j;
                int rowbase = (r < 4) ? ((n * R_REL + r) * D_DIM) : (n * D_DIM);
                const float4 m = *(const float4*)&m_lds[rowbase + d4];
                float a = (j == 0) ? acc0 : (j == 1) ? acc1 : (j == 2) ? acc2 : acc3;
                a = fmaf(m.x, w0, a);
                a = fmaf(m.y, w1, a);
                a = fmaf(m.z, w2, a);
                a = fmaf(m.w, w3, a);
                if (j == 0) acc0 = a; else if (j == 1) acc1 = a;
                else if (j == 2) acc2 = a; else acc3 = a;
            }
        }
        __syncthreads();
    }

    // ---- epilogue: bf16 out ----
    float b = bias[lane];
#pragma unroll
    for (int j = 0; j < 4; ++j) {
        float a = (j == 0) ? acc0 : (j == 1) ? acc1 : (j == 2) ? acc2 : acc3;
        float v = a + b;
        if (RELU) v = fmaxf(v, 0.f);
        int n = nbase + wid + 16 * j;
        hb_out[(size_t)n * D_DIM + lane] = to_bf16(v);
    }
}

// ---------------- pooling: run-accumulated (batch is sorted), bf16 input ----------------

__global__ __launch_bounds__(1024) void k_pool(const unsigned short* __restrict__ hb,
                                               const int* __restrict__ batch,
                                               float* __restrict__ partial) {
    __shared__ float bin[G_GRAPHS * D_DIM];   // 16 KB
    int tid = threadIdx.x, lane = tid & 63, wid = tid >> 6;
    for (int i = tid; i < G_GRAPHS * D_DIM; i += 1024) bin[i] = 0.f;
    __syncthreads();
    const int per = (N_NODES + POOL_BLOCKS - 1) / POOL_BLOCKS;
    int n0 = blockIdx.x * per;
    int n1 = n0 + per; if (n1 > N_NODES) n1 = N_NODES;
    int cntw = n1 - n0;
    int sub = (cntw + 15) >> 4;
    int w0 = n0 + wid * sub;
    int w1 = w0 + sub; if (w1 > n1) w1 = n1;

    float acc = 0.f;
    int cur = -1;
    for (int n = w0; n < w1; ++n) {
        int b = __builtin_amdgcn_readfirstlane(batch[n]);
        unsigned int u = hb[(size_t)n * D_DIM + lane];
        float v = __uint_as_float(u << 16);
        if (b != cur) {
            if (cur >= 0) atomicAdd(&bin[cur * D_DIM + lane], acc);
            cur = b;
            acc = v;
        } else {
            acc += v;
        }
    }
    if (cur >= 0) atomicAdd(&bin[cur * D_DIM + lane], acc);
    __syncthreads();
    for (int i = tid; i < G_GRAPHS * D_DIM; i += 1024)
        partial[blockIdx.x * (G_GRAPHS * D_DIM) + i] = bin[i];
}

__global__ void k_pool_reduce(const float* __restrict__ partial,
                              float* __restrict__ pooled) {
    int i = blockIdx.x * blockDim.x + threadIdx.x;   // 4096
    if (i < G_GRAPHS * D_DIM) {
        float s = 0.f;
        for (int b = 0; b < POOL_BLOCKS; ++b) s += partial[b * (G_GRAPHS * D_DIM) + i];
        pooled[i] = s;
    }
}

// ---------------- head ----------------

__global__ void k_head(const float* __restrict__ pooled, const int* __restrict__ start,
                       const float* __restrict__ fc1w, const float* __restrict__ fc1b,
                       const float* __restrict__ fc2w, const float* __restrict__ fc2b,
                       float* __restrict__ out) {
    __shared__ float p[G_GRAPHS][D_DIM];
    __shared__ float hf[G_GRAPHS][D_DIM];
    __shared__ float sc[G_GRAPHS][C_CLS];
    int t = threadIdx.x;

    for (int i = t; i < G_GRAPHS * D_DIM; i += 1024) {
        int g = i >> 6;
        int c = start[g + 1] - start[g];
        p[g][i & 63] = pooled[i] / (float)(c > 0 ? c : 1);
    }
    __syncthreads();

    for (int i = t; i < G_GRAPHS * D_DIM; i += 1024) {
        int g = i >> 6, o = i & 63;
        float a = fc1b[o];
#pragma unroll
        for (int d = 0; d < D_DIM; ++d) a = fmaf(p[g][d], fc1w[d * D_DIM + o], a);
        hf[g][o] = fmaxf(a, 0.f);
    }
    __syncthreads();

    if (t < G_GRAPHS * C_CLS) {
        int g = t / C_CLS, c = t % C_CLS;
        float a = fc2b[c];
#pragma unroll
        for (int d = 0; d < D_DIM; ++d) a = fmaf(hf[g][d], fc2w[d * C_CLS + c], a);
        sc[g][c] = a;
    }
    __syncthreads();

    if (t < G_GRAPHS) {
        float m = -1e30f;
#pragma unroll
        for (int c = 0; c < C_CLS; ++c) m = fmaxf(m, sc[t][c]);
        float s = 0.f;
#pragma unroll
        for (int c = 0; c < C_CLS; ++c) s += expf(sc[t][c] - m);
        float lse = m + logf(s);
#pragma unroll
        for (int c = 0; c < C_CLS; ++c) out[t * C_CLS + c] = sc[t][c] - lse;
    }
}

// ---------------- launch ----------------
// ws budget (~183.5 MB, < known-good 187 MB from round 4):
// cnt 3.2 + off 3.2 + cursor 3.2 + invc 3.2 + srcSorted 16 + hb0 25.6 +
// hb1 25.6 + mbuf 102.4 + partial 2.1 + small

extern "C" void kernel_launch(void* const* d_in, const int* in_sizes, int n_in,
                              void* d_out, int out_size, void* d_ws, size_t ws_size,
                              hipStream_t stream) {
    const int*   x_op    = (const int*)d_in[0];
    const int*   x_cat   = (const int*)d_in[1];
    const int*   eidx    = (const int*)d_in[2];
    const int*   src     = eidx;
    const int*   tgt     = eidx + N_EDGES;
    const int*   etype   = (const int*)d_in[3];
    const int*   batch   = (const int*)d_in[4];
    const float* op_emb  = (const float*)d_in[5];
    const float* cat_emb = (const float*)d_in[6];
    const float* w1 = (const float*)d_in[7];
    const float* r1 = (const float*)d_in[8];
    const float* b1 = (const float*)d_in[9];
    const float* w2 = (const float*)d_in[10];
    const float* r2 = (const float*)d_in[11];
    const float* b2 = (const float*)d_in[12];
    const float* w3 = (const float*)d_in[13];
    const float* r3 = (const float*)d_in[14];
    const float* b3 = (const float*)d_in[15];
    const float* fc1w = (const float*)d_in[16];
    const float* fc1b = (const float*)d_in[17];
    const float* fc2w = (const float*)d_in[18];
    const float* fc2b = (const float*)d_in[19];
    float* out = (float*)d_out;

    char* ws = (char*)d_ws;
    size_t o = 0;
    auto alloc = [&](size_t bytes) -> void* {
        o = (o + 255) & ~(size_t)255;
        void* p = ws + o;
        o += bytes;
        return p;
    };

    int*   cnt        = (int*)alloc((size_t)NR * 4);
    int*   off        = (int*)alloc((size_t)(NR + 1) * 4);
    int*   cursor     = (int*)alloc((size_t)NR * 4);
    float* invc       = (float*)alloc((size_t)NR * 4);
    int*   bsum       = (int*)alloc((size_t)NB * 4 + 256);
    int*   srcSorted  = (int*)alloc((size_t)N_EDGES * 4);
    unsigned short* hb0  = (unsigned short*)alloc((size_t)N_NODES * D_DIM * 2);
    unsigned short* hb1  = (unsigned short*)alloc((size_t)N_NODES * D_DIM * 2);
    unsigned short* mbuf = (unsigned short*)alloc((size_t)NR * D_DIM * 2);
    float* partial    = (float*)alloc((size_t)POOL_BLOCKS * G_GRAPHS * D_DIM * 4);
    float* pooled     = (float*)alloc((size_t)G_GRAPHS * D_DIM * 4);
    int*   startg     = (int*)alloc((size_t)(G_GRAPHS + 1) * 4);

    hipMemsetAsync(cnt, 0, (size_t)NR * 4, stream);

    k_count<<<(N_EDGES + 255) / 256, 256, 0, stream>>>(tgt, etype, cnt);
    k_scan1<<<NB, 256, 0, stream>>>(cnt, off, bsum);
    k_scan2<<<1, 256, 0, stream>>>(bsum);
    k_scan3<<<(NR + 255) / 256, 256, 0, stream>>>(cnt, off, bsum, cursor, invc);
    k_scatter<<<(N_EDGES + 255) / 256, 256, 0, stream>>>(src, tgt, etype, cursor, srcSorted);

    k_embed<<<(N_NODES * 16 + 255) / 256, 256, 0, stream>>>(
        x_op, x_cat, (const float4*)op_emb, (const float4*)cat_emb, (ushort4*)hb0);
    k_bounds<<<(N_NODES + 255) / 256, 256, 0, stream>>>(batch, startg);

    const int aggBlocks  = NR / 8 / 4;           // 25000 (4 waves/block)
    const int gemmBlocks = N_NODES / LBN;        // 3125

    // layer 1
    k_agg<<<aggBlocks, 256, 0, stream>>>(hb0, off, srcSorted, invc, mbuf);
    k_trans<1><<<gemmBlocks, 1024, 0, stream>>>(hb0, mbuf, hb1, w1, r1, b1);
    // layer 2
    k_agg<<<aggBlocks, 256, 0, stream>>>(hb1, off, srcSorted, invc, mbuf);
    k_trans<1><<<gemmBlocks, 1024, 0, stream>>>(hb1, mbuf, hb0, w2, r2, b2);
    // layer 3
    k_agg<<<aggBlocks, 256, 0, stream>>>(hb0, off, srcSorted, invc, mbuf);
    k_trans<0><<<gemmBlocks, 1024, 0, stream>>>(hb0, mbuf, hb1, w3, r3, b3);

    k_pool<<<POOL_BLOCKS, 1024, 0, stream>>>(hb1, batch, partial);
    k_pool_reduce<<<(G_GRAPHS * D_DIM + 255) / 256, 256, 0, stream>>>(partial, pooled);
    k_head<<<1, 1024, 0, stream>>>(pooled, startg, fc1w, fc1b, fc2w, fc2b, out);
}